// Round 2
// baseline (124.547 us; speedup 1.0000x reference)
//
#include <hip/hip_runtime.h>

// IntLayerNorm (quantized), D=1024. One 256-thread block per row, 4 elems/thread.
// Memory-bound: 64MB read + 64MB write -> target ~6 TB/s.
// NOTE: harness passes integer inputs as int32 -> LUT is const int*, not int64.

constexpr int Dn   = 1024;
constexpr int QD   = 16;   // Q_D
constexpr int INVD = 64;   // round(2^16 / 1024)
constexpr int QLUT = 15;
// Q_W = 8 -> scale 256, output divide 1/256

__global__ __launch_bounds__(256) void intln_kernel(
    const float* __restrict__ x,
    const float* __restrict__ w,
    const float* __restrict__ b,
    const int* __restrict__ lut,         // 32 x int32 (harness converts ints to int32)
    float* __restrict__ out,
    int nrows)
{
    const int row = blockIdx.x;
    if (row >= nrows) return;
    const int tid = threadIdx.x;
    const size_t base = (size_t)row * Dn + tid * 4;

    // ---- load + round (half-to-even, matches jnp.round) ----
    const float4 xv = *reinterpret_cast<const float4*>(x + base);
    const int x0 = __float2int_rn(xv.x);
    const int x1 = __float2int_rn(xv.y);
    const int x2 = __float2int_rn(xv.z);
    const int x3 = __float2int_rn(xv.w);

    long long s  = (long long)(x0 + x1 + x2 + x3);
    long long ss = (long long)x0 * x0 + (long long)x1 * x1
                 + (long long)x2 * x2 + (long long)x3 * x3;

    // ---- wave (64-lane) shuffle reduce ----
#pragma unroll
    for (int off = 32; off; off >>= 1) {
        s  += __shfl_down(s,  off, 64);
        ss += __shfl_down(ss, off, 64);
    }

    __shared__ long long sh_s[4], sh_ss[4];
    if ((tid & 63) == 0) { sh_s[tid >> 6] = s; sh_ss[tid >> 6] = ss; }
    __syncthreads();

    // every thread finishes the reduction (4 values) -> no second barrier
    const long long S  = sh_s[0]  + sh_s[1]  + sh_s[2]  + sh_s[3];
    const long long SS = sh_ss[0] + sh_ss[1] + sh_ss[2] + sh_ss[3];

    const long long mean = (S * INVD) >> QD;            // arithmetic shift, matches jax int64
    // exact: sum((x-m)^2) = SS - 2*m*S + D*m^2  (SHIFT==0 so y_shifted==y_int)
    const long long sum_sq = SS - 2 * mean * S + (long long)Dn * mean * mean;
    long long var = (sum_sq * INVD) >> QD;
    if (var < 1) var = 1;

    // k = trunc(log2f(var)); exact floor via clz — identical to f32 path for var < 2^24
    const int k  = 63 - __clzll((unsigned long long)var);
    const int sa = k - 4;                                // M = 4
    const int mant = (sa >= 0) ? (int)((var >> sa) & 15)
                               : (int)((var << (-sa)) & 15);
    const int idx = ((k & 1) << 4) | mant;
    const long long inv = (long long)lut[idx];           // uniform addr -> cache broadcast
    const int tot = (k >> 1) + QLUT;                     // p + SHIFT(0) + Q_LUT

    // ---- per-element output ----
    const float4 wv = *reinterpret_cast<const float4*>(w + tid * 4);
    const float4 bv = *reinterpret_cast<const float4*>(b + tid * 4);
    const long long w0 = __float2int_rn(wv.x * 256.0f);
    const long long w1 = __float2int_rn(wv.y * 256.0f);
    const long long w2 = __float2int_rn(wv.z * 256.0f);
    const long long w3 = __float2int_rn(wv.w * 256.0f);
    const long long b0 = __float2int_rn(bv.x * 256.0f);
    const long long b1 = __float2int_rn(bv.y * 256.0f);
    const long long b2 = __float2int_rn(bv.z * 256.0f);
    const long long b3 = __float2int_rn(bv.w * 256.0f);

    float4 ov;
    ov.x = (float)((((x0 - mean) * inv * w0) >> tot) + b0) * 0.00390625f;
    ov.y = (float)((((x1 - mean) * inv * w1) >> tot) + b1) * 0.00390625f;
    ov.z = (float)((((x2 - mean) * inv * w2) >> tot) + b2) * 0.00390625f;
    ov.w = (float)((((x3 - mean) * inv * w3) >> tot) + b3) * 0.00390625f;
    *reinterpret_cast<float4*>(out + base) = ov;
}

extern "C" void kernel_launch(void* const* d_in, const int* in_sizes, int n_in,
                              void* d_out, int out_size, void* d_ws, size_t ws_size,
                              hipStream_t stream) {
    const float* x   = (const float*)d_in[0];
    const float* w   = (const float*)d_in[1];
    const float* b   = (const float*)d_in[2];
    const int*   lut = (const int*)d_in[3];   // int32 on device
    float* out = (float*)d_out;

    const int nrows = in_sizes[0] / Dn;   // 8*2048 = 16384
    intln_kernel<<<nrows, 256, 0, stream>>>(x, w, b, lut, out, nrows);
}

// Round 3
// 114.990 us; speedup vs baseline: 1.0831x; 1.0831x over previous
//
#include <hip/hip_runtime.h>

// IntLayerNorm (quantized), D=1024. ONE WAVE PER ROW: 64 lanes x 16 elems,
// barrier-free shfl_xor reduce, 32-bit element math, int64 only for the
// uniform per-row tail and the final widening multiply. Memory-bound:
// 64MB read + 64MB write -> target ~6 TB/s.

constexpr int Dn   = 1024;
constexpr int QD   = 16;   // Q_D
constexpr int INVD = 64;   // round(2^16 / 1024)
constexpr int QLUT = 15;
// Q_W = 8 -> scale 256, output divide 1/256

__global__ __launch_bounds__(256) void intln_kernel(
    const float* __restrict__ x,
    const float* __restrict__ w,
    const float* __restrict__ b,
    const int* __restrict__ lut,         // 32 x int32
    float* __restrict__ out,
    int nrows)
{
    const int lane = threadIdx.x & 63;
    const int wid  = threadIdx.x >> 6;          // 0..3, each wave owns a row
    const int row  = blockIdx.x * 4 + wid;
    if (row >= nrows) return;

    const size_t rbase = (size_t)row * Dn;
    const int    coff  = lane * 4;              // within-chunk offset

    // ---- load x: 4 coalesced float4 chunks (lane*16B, 1KB/wave/instr) ----
    float4 xv0 = *reinterpret_cast<const float4*>(x + rbase + 0   + coff);
    float4 xv1 = *reinterpret_cast<const float4*>(x + rbase + 256 + coff);
    float4 xv2 = *reinterpret_cast<const float4*>(x + rbase + 512 + coff);
    float4 xv3 = *reinterpret_cast<const float4*>(x + rbase + 768 + coff);
    // w/b chunks (L1/L2-resident after first blocks) — issue early
    float4 wv0 = *reinterpret_cast<const float4*>(w + 0   + coff);
    float4 wv1 = *reinterpret_cast<const float4*>(w + 256 + coff);
    float4 wv2 = *reinterpret_cast<const float4*>(w + 512 + coff);
    float4 wv3 = *reinterpret_cast<const float4*>(w + 768 + coff);
    float4 bv0 = *reinterpret_cast<const float4*>(b + 0   + coff);
    float4 bv1 = *reinterpret_cast<const float4*>(b + 256 + coff);
    float4 bv2 = *reinterpret_cast<const float4*>(b + 512 + coff);
    float4 bv3 = *reinterpret_cast<const float4*>(b + 768 + coff);

    int xi[16];
    xi[0]=__float2int_rn(xv0.x); xi[1]=__float2int_rn(xv0.y); xi[2]=__float2int_rn(xv0.z); xi[3]=__float2int_rn(xv0.w);
    xi[4]=__float2int_rn(xv1.x); xi[5]=__float2int_rn(xv1.y); xi[6]=__float2int_rn(xv1.z); xi[7]=__float2int_rn(xv1.w);
    xi[8]=__float2int_rn(xv2.x); xi[9]=__float2int_rn(xv2.y); xi[10]=__float2int_rn(xv2.z); xi[11]=__float2int_rn(xv2.w);
    xi[12]=__float2int_rn(xv3.x); xi[13]=__float2int_rn(xv3.y); xi[14]=__float2int_rn(xv3.z); xi[15]=__float2int_rn(xv3.w);

    int s = 0, ss = 0;                          // per-lane partials fit int32 easily
#pragma unroll
    for (int j = 0; j < 16; ++j) { s += xi[j]; ss += xi[j] * xi[j]; }

    // ---- wave butterfly reduce (all lanes end with full sums), int32 ----
#pragma unroll
    for (int off = 32; off; off >>= 1) {
        s  += __shfl_xor(s,  off, 64);
        ss += __shfl_xor(ss, off, 64);
    }

    // ---- uniform per-row tail: int64, bit-exact vs reference ----
    const long long S  = s;
    const long long SS = ss;
    const long long mean64 = (S * INVD) >> QD;                    // fixed-point mean
    const long long sum_sq = SS - 2 * mean64 * S + (long long)Dn * mean64 * mean64;
    long long var = (sum_sq * INVD) >> QD;
    if (var < 1) var = 1;

    const int k  = 63 - __clzll((unsigned long long)var);         // floor(log2(var))
    const int sa = k - 4;                                         // M = 4
    const int mant = (sa >= 0) ? (int)((var >> sa) & 15)
                               : (int)((var << (-sa)) & 15);
    const int idx = ((k & 1) << 4) | mant;
    const int inv = lut[idx];                                     // uniform addr
    const int tot = (k >> 1) + QLUT;                              // p + SHIFT(0) + Q_LUT
    const int mean = (int)mean64;

    // ---- per-element: 32-bit y*inv, one 32x32->64 widening mul, shift ----
    float ov[16];
#pragma unroll
    for (int j = 0; j < 16; ++j) {
        const float wf = (j<4 ? (&wv0.x)[j] : j<8 ? (&wv1.x)[j-4] : j<12 ? (&wv2.x)[j-8] : (&wv3.x)[j-12]);
        const float bf = (j<4 ? (&bv0.x)[j] : j<8 ? (&bv1.x)[j-4] : j<12 ? (&bv2.x)[j-8] : (&bv3.x)[j-12]);
        const int wq = __float2int_rn(wf * 256.0f);
        const int bq = __float2int_rn(bf * 256.0f);
        const int yi = xi[j] - mean;                  // |yi| small
        const int t  = yi * inv;                      // fits int32 (|yi|*2^15 < 2^31)
        const long long prod = (long long)t * wq;     // 32x32->64
        ov[j] = (float)((int)(prod >> tot) + bq) * 0.00390625f;
    }

    float4 o0 = { ov[0], ov[1], ov[2], ov[3] };
    float4 o1 = { ov[4], ov[5], ov[6], ov[7] };
    float4 o2 = { ov[8], ov[9], ov[10], ov[11] };
    float4 o3 = { ov[12], ov[13], ov[14], ov[15] };
    *reinterpret_cast<float4*>(out + rbase + 0   + coff) = o0;
    *reinterpret_cast<float4*>(out + rbase + 256 + coff) = o1;
    *reinterpret_cast<float4*>(out + rbase + 512 + coff) = o2;
    *reinterpret_cast<float4*>(out + rbase + 768 + coff) = o3;
}

extern "C" void kernel_launch(void* const* d_in, const int* in_sizes, int n_in,
                              void* d_out, int out_size, void* d_ws, size_t ws_size,
                              hipStream_t stream) {
    const float* x   = (const float*)d_in[0];
    const float* w   = (const float*)d_in[1];
    const float* b   = (const float*)d_in[2];
    const int*   lut = (const int*)d_in[3];
    float* out = (float*)d_out;

    const int nrows = in_sizes[0] / Dn;          // 8*2048 = 16384
    const int blocks = (nrows + 3) / 4;          // 4 rows (waves) per block
    intln_kernel<<<blocks, 256, 0, stream>>>(x, w, b, lut, out, nrows);
}